// Round 16
// baseline (263.829 us; speedup 1.0000x reference)
//
#include <hip/hip_runtime.h>
#include <hip/hip_bf16.h>
#include <stdint.h>

#define BB 2
#define SS 2048
#define HH 1024
#define NHH 16
#define HDD 64
#define MM (BB*SS)      // 4096
#define N1 (3*HH)       // 3072
#define LOG2E 1.44269504f

using bf16 = __hip_bfloat16;
typedef __attribute__((ext_vector_type(8))) short bf16x8;
typedef __attribute__((ext_vector_type(4))) float f32x4;
typedef __attribute__((ext_vector_type(16))) float f32x16;

__device__ inline unsigned short f2bfu(float f) {
  union { bf16 h; unsigned short u; } c;
  c.h = __float2bfloat16(f);
  return c.u;
}

// hardware packed f32->bf16 (RNE), src0 -> low16, src1 -> high16 (T12 recipe)
__device__ inline unsigned int cvtpk(float lo, float hi) {
  unsigned int r;
  asm("v_cvt_pk_bf16_f32 %0, %1, %2" : "=v"(r) : "v"(lo), "v"(hi));
  return r;
}

__device__ inline void load_lds16(const void* g, void* l) {
  __builtin_amdgcn_global_load_lds(
      (const __attribute__((address_space(1))) void*)g,
      (__attribute__((address_space(3))) void*)l, 16, 0, 0);
}

__device__ inline f32x4 mfma16(bf16x8 a, bf16x8 b, f32x4 c) {
  return __builtin_amdgcn_mfma_f32_16x16x32_bf16(a, b, c, 0, 0, 0);
}
__device__ inline f32x16 mfma32(bf16x8 a, bf16x8 b, f32x16 c) {
  return __builtin_amdgcn_mfma_f32_32x32x16_bf16(a, b, c, 0, 0, 0);
}

// ---------------- fused fp32 -> bf16 convert (3 buffers, one launch) ----------------
__global__ __launch_bounds__(256) void cvt3_f32_bf16(const float* __restrict__ a,
                                                     unsigned short* __restrict__ ao, int na4,
                                                     const float* __restrict__ bsrc,
                                                     unsigned short* __restrict__ bo, int nb4,
                                                     const float* __restrict__ c,
                                                     unsigned short* __restrict__ co, int nc4) {
  int total = na4 + nb4 + nc4;
  int st = gridDim.x * blockDim.x;
  for (int i = blockIdx.x * blockDim.x + threadIdx.x; i < total; i += st) {
    const float* in; unsigned short* out; int j = i;
    if (j < na4) { in = a; out = ao; }
    else if (j < na4 + nb4) { j -= na4; in = bsrc; out = bo; }
    else { j -= na4 + nb4; in = c; out = co; }
    float4 v = reinterpret_cast<const float4*>(in)[j];
    ushort4 o;
    o.x = f2bfu(v.x); o.y = f2bfu(v.y); o.z = f2bfu(v.z); o.w = f2bfu(v.w);
    reinterpret_cast<ushort4*>(out)[j] = o;
  }
}

// ---------------- mask tile flags: 1 if 64x64 tile is all ones ----------------
__global__ __launch_bounds__(256) void mask_flags_kernel(const float* __restrict__ mask,
                                                         unsigned char* __restrict__ flags) {
  int t = blockIdx.x;
  int b = t >> 10, qt = (t >> 5) & 31, kt = t & 31;
  const float* mb = mask + ((size_t)b * SS + qt * 64) * SS + kt * 64;
  int row = threadIdx.x >> 2, c0 = (threadIdx.x & 3) * 16;
  int ok = 1;
#pragma unroll
  for (int j = 0; j < 4; ++j) {
    float4 v = *reinterpret_cast<const float4*>(mb + (size_t)row * SS + c0 + j * 4);
    ok &= (v.x == 1.f) & (v.y == 1.f) & (v.z == 1.f) & (v.w == 1.f);
  }
  ok = __all(ok);
  __shared__ int s[4];
  if ((threadIdx.x & 63) == 0) s[threadIdx.x >> 6] = ok;
  __syncthreads();
  if (threadIdx.x == 0) flags[t] = (unsigned char)(s[0] & s[1] & s[2] & s[3]);
}

// ---------------- V transpose: mixed V-cols -> vT[b][h][d][s] ----------------
__global__ __launch_bounds__(256) void vtrans_kernel(const unsigned short* __restrict__ mixed,
                                                     unsigned short* __restrict__ vT) {
  __shared__ unsigned short t[64 * 72];
  const int st = blockIdx.x, bh = blockIdx.y;
  const int b = bh >> 4, h = bh & 15;
  const int r = threadIdx.x >> 2, c0 = (threadIdx.x & 3) * 16;

  const unsigned short* src = mixed + ((size_t)(b * SS) + st * 64) * N1 + h * 192 + 128;
  union { bf16x8 v; unsigned short u[8]; } A, B;
  A.v = *reinterpret_cast<const bf16x8*>(src + (size_t)r * N1 + c0);
  B.v = *reinterpret_cast<const bf16x8*>(src + (size_t)r * N1 + c0 + 8);
#pragma unroll
  for (int j = 0; j < 8; ++j) t[(c0 + j) * 72 + r] = A.u[j];
#pragma unroll
  for (int j = 0; j < 8; ++j) t[(c0 + 8 + j) * 72 + r] = B.u[j];
  __syncthreads();

  unsigned short* dst = vT + ((size_t)bh * HDD + r) * SS + st * 64 + c0;
  bf16x8 o0 = *reinterpret_cast<const bf16x8*>(&t[r * 72 + c0]);
  bf16x8 o1 = *reinterpret_cast<const bf16x8*>(&t[r * 72 + c0 + 8]);
  *reinterpret_cast<bf16x8*>(dst) = o0;
  *reinterpret_cast<bf16x8*>(dst + 8) = o1;
}

// ---------------- GEMM (R13, verified): 128x128, BK=64, XOR-swizzled LDS ------------
template <bool OUT_BF16>
__global__ __launch_bounds__(256) void gemm_bt(const unsigned short* __restrict__ A,
                                               const unsigned short* __restrict__ Bt,
                                               const float* __restrict__ bias,
                                               void* __restrict__ Cv,
                                               int Ndim, int Kdim) {
  __shared__ __align__(16) unsigned short As[128 * 64];
  __shared__ __align__(16) unsigned short Bs[128 * 64];

  const int tid = threadIdx.x;
  const int wave = tid >> 6, lane = tid & 63;
  const int m0 = blockIdx.x * 128;
  const int n0 = blockIdx.y * 128;
  const int wm = (wave >> 1) * 64, wn = (wave & 1) * 64;
  const int lrow = lane & 15;
  const int g = lane >> 4;
  const int r4 = (lane >> 4) * 4;
  const int x0 = (g ^ (lrow & 7)) << 3;
  const int x1 = ((g + 4) ^ (lrow & 7)) << 3;

  f32x4 acc[4][4];
  const f32x4 z = {0.f, 0.f, 0.f, 0.f};
  for (int i = 0; i < 4; ++i)
    for (int j = 0; j < 4; ++j) acc[i][j] = z;

  for (int k0 = 0; k0 < Kdim; k0 += 64) {
#pragma unroll
    for (int it = 0; it < 4; ++it) {
      int idx = it * 256 + tid;
      int row = idx >> 3, seg = idx & 7;
      int sw = (seg ^ (row & 7)) << 3;
      load_lds16(A + (size_t)(m0 + row) * Kdim + k0 + sw, &As[row * 64 + seg * 8]);
      load_lds16(Bt + (size_t)(n0 + row) * Kdim + k0 + sw, &Bs[row * 64 + seg * 8]);
    }
    __syncthreads();

    bf16x8 af[4], bfr[4];
#pragma unroll
    for (int i = 0; i < 4; ++i)
      af[i] = *reinterpret_cast<const bf16x8*>(&As[(wm + i * 16 + lrow) * 64 + x0]);
#pragma unroll
    for (int j = 0; j < 4; ++j)
      bfr[j] = *reinterpret_cast<const bf16x8*>(&Bs[(wn + j * 16 + lrow) * 64 + x0]);
#pragma unroll
    for (int i = 0; i < 4; ++i)
#pragma unroll
      for (int j = 0; j < 4; ++j)
        acc[i][j] = mfma16(af[i], bfr[j], acc[i][j]);
#pragma unroll
    for (int i = 0; i < 4; ++i)
      af[i] = *reinterpret_cast<const bf16x8*>(&As[(wm + i * 16 + lrow) * 64 + x1]);
#pragma unroll
    for (int j = 0; j < 4; ++j)
      bfr[j] = *reinterpret_cast<const bf16x8*>(&Bs[(wn + j * 16 + lrow) * 64 + x1]);
#pragma unroll
    for (int i = 0; i < 4; ++i)
#pragma unroll
      for (int j = 0; j < 4; ++j)
        acc[i][j] = mfma16(af[i], bfr[j], acc[i][j]);
    __syncthreads();
  }

#pragma unroll
  for (int i = 0; i < 4; ++i) {
#pragma unroll
    for (int j = 0; j < 4; ++j) {
      int col = n0 + wn + j * 16 + lrow;
      float bv = bias[col];
#pragma unroll
      for (int r = 0; r < 4; ++r) {
        int row = m0 + wm + i * 16 + r4 + r;
        float v = acc[i][j][r] + bv;
        if (OUT_BF16) {
          ((unsigned short*)Cv)[(size_t)row * Ndim + col] = f2bfu(v);
        } else {
          ((float*)Cv)[(size_t)row * Ndim + col] = v;
        }
      }
    }
  }
}

// ---------------- Flash attention: 32x32 swapped QK^T + split-K, max-free -----------
// Block 512 thr = 8 waves: wave (qg = w&3, kh = w>>2) handles q-rows qg*32..+31 of
// the 128-row Q-block, kv-tiles kh*16..kh*16+15. Grid (16, B*NH) -> 4096 waves.
// QK^T swapped: D[krow][q], q = lane&31; C/D row = (r&3)+8*(r>>2)+4*(lane>>5)
// (m74/m101; VERIFIED end-to-end by R4's passing run, as is the cvtpk+shfl_xor(32)
// P repack below). Max-free softmax (R9, verified) => split-K merge is a pure add.
__global__ void attn_kernel(const unsigned short* __restrict__ mixed,
                            const unsigned short* __restrict__ vT,
                            const float* __restrict__ mask,
                            const unsigned char* __restrict__ flags,
                            unsigned short* __restrict__ ctx) {
  __shared__ __align__(16) unsigned short Ks[2][2][64 * 64];  // [kh][buf]
  __shared__ __align__(16) unsigned short Vs[2][2][64 * 64];  // [kh][buf], [d][s]

  const int tid = threadIdx.x, wave = tid >> 6, lane = tid & 63;
  const int qg = wave & 3, kh = wave >> 2;
  const int l31 = lane & 31, h = lane >> 5;
  const int q0 = blockIdx.x * 128;
  const int bh = blockIdx.y;
  const int b = bh / NHH, hh = bh % NHH;

  const unsigned short* qbase = mixed + (size_t)(b * SS) * N1 + hh * 192;
  const unsigned short* kbase = qbase + 64;
  const unsigned short* vtbase = vT + ((size_t)(b * NHH + hh) * HDD) * SS;  // [d][s]
  const float* mbase = mask + (size_t)b * SS * SS;
  const unsigned char* fl = flags + ((size_t)b * 32 + blockIdx.x * 2 + (qg >> 1)) * 32 + kh * 16;

  const int srow = (tid >> 3) & 63, sseg = tid & 7;
  const int sw = (sseg ^ (srow & 7)) << 3;

  // ---- prologue 1: stage Q (128x64) into Ks scratch, hoist fragments ----
  {
    unsigned short* Qtmp = &Ks[0][0][0];   // 16KB transient
    load_lds16(qbase + (size_t)(q0 + srow) * N1 + sw, &Qtmp[srow * 64 + sseg * 8]);
    load_lds16(qbase + (size_t)(q0 + 64 + srow) * N1 + sw, &Qtmp[(64 + srow) * 64 + sseg * 8]);
  }
  __syncthreads();
  const int qrow = qg * 32 + l31;
  const int xq = l31 & 7;
  // per-step swizzled seg offsets (elems); same formula serves Q, K, V reads
  const int o0 = ((2 * 0 + h) ^ xq) << 3;
  const int o1 = ((2 * 1 + h) ^ xq) << 3;
  const int o2 = ((2 * 2 + h) ^ xq) << 3;
  const int o3 = ((2 * 3 + h) ^ xq) << 3;
  bf16x8 qf0, qf1, qf2, qf3;
  {
    const unsigned short* Qtmp = &Ks[0][0][0];
    qf0 = *reinterpret_cast<const bf16x8*>(&Qtmp[qrow * 64 + o0]);
    qf1 = *reinterpret_cast<const bf16x8*>(&Qtmp[qrow * 64 + o1]);
    qf2 = *reinterpret_cast<const bf16x8*>(&Qtmp[qrow * 64 + o2]);
    qf3 = *reinterpret_cast<const bf16x8*>(&Qtmp[qrow * 64 + o3]);
  }
  __syncthreads();

  // ---- prologue 2: stage K0/V0 for both halves ----
  load_lds16(kbase + (size_t)srow * N1 + sw,          &Ks[0][0][srow * 64 + sseg * 8]);
  load_lds16(kbase + (size_t)(1024 + srow) * N1 + sw, &Ks[1][0][srow * 64 + sseg * 8]);
  load_lds16(vtbase + (size_t)srow * SS + sw,         &Vs[0][0][srow * 64 + sseg * 8]);
  load_lds16(vtbase + (size_t)srow * SS + 1024 + sw,  &Vs[1][0][srow * 64 + sseg * 8]);
  __syncthreads();

  // ---- per-wave read bases (this wave's kh half) ----
  const unsigned short* KrA = &Ks[kh][0][l31 * 64];          // krow = l31      (+CUR*4096)
  const unsigned short* KrB = &Ks[kh][0][(32 + l31) * 64];   // krow = 32+l31
  const unsigned short* Vr0 = &Vs[kh][0][l31 * 64];          // d = l31         (+CUR*4096)
  const unsigned short* Vr1 = &Vs[kh][0][(32 + l31) * 64];   // d = 32+l31

  // ---- loop-carried staging prefetch pointers ----
  const unsigned short* kp0 = kbase + (size_t)(64 + srow) * N1 + sw;
  const unsigned short* kp1 = kbase + (size_t)(1088 + srow) * N1 + sw;
  const unsigned short* vp0 = vtbase + (size_t)srow * SS + 64 + sw;
  const unsigned short* vp1 = vtbase + (size_t)srow * SS + 1088 + sw;

  f32x16 oacc0, oacc1;
#pragma unroll
  for (int i = 0; i < 16; ++i) { oacc0[i] = 0.f; oacc1[i] = 0.f; }
  float lsum = 0.f;
  const float C2 = 0.125f * LOG2E;

#define TILE(CUR_, I_, HAVENEXT_)                                               \
  {                                                                             \
    const int i_ = (I_);                                                        \
    if (HAVENEXT_) {                                                            \
      load_lds16(kp0, &Ks[0][(CUR_)^1][srow * 64 + sseg * 8]);                  \
      load_lds16(kp1, &Ks[1][(CUR_)^1][srow * 64 + sseg * 8]);                  \
      load_lds16(vp0, &Vs[0][(CUR_)^1][srow * 64 + sseg * 8]);                  \
      load_lds16(vp1, &Vs[1][(CUR_)^1][srow * 64 + sseg * 8]);                  \
    }                                                                           \
    kp0 += 64 * N1; kp1 += 64 * N1; vp0 += 64; vp1 += 64;                       \
    f32x16 sa0, sa1;                                                            \
    {                                                                           \
      bf16x8 kA0 = *reinterpret_cast<const bf16x8*>(KrA + (CUR_)*4096 + o0);    \
      bf16x8 kB0 = *reinterpret_cast<const bf16x8*>(KrB + (CUR_)*4096 + o0);    \
      bf16x8 kA1 = *reinterpret_cast<const bf16x8*>(KrA + (CUR_)*4096 + o1);    \
      bf16x8 kB1 = *reinterpret_cast<const bf16x8*>(KrB + (CUR_)*4096 + o1);    \
      bf16x8 kA2 = *reinterpret_cast<const bf16x8*>(KrA + (CUR_)*4096 + o2);    \
      bf16x8 kB2 = *reinterpret_cast<const bf16x8*>(KrB + (CUR_)*4096 + o2);    \
      bf16x8 kA3 = *reinterpret_cast<const bf16x8*>(KrA + (CUR_)*4096 + o3);    \
      bf16x8 kB3 = *reinterpret_cast<const bf16x8*>(KrB + (CUR_)*4096 + o3);    \
      __builtin_amdgcn_s_setprio(1);                                           \
      f32x16 zz;                                                                \
      _Pragma("unroll")                                                         \
      for (int i = 0; i < 16; ++i) zz[i] = 0.f;                                 \
      sa0 = mfma32(kA0, qf0, zz);  sa1 = mfma32(kB0, qf0, zz);                  \
      sa0 = mfma32(kA1, qf1, sa0); sa1 = mfma32(kB1, qf1, sa1);                 \
      sa0 = mfma32(kA2, qf2, sa0); sa1 = mfma32(kB2, qf2, sa1);                 \
      sa0 = mfma32(kA3, qf3, sa0); sa1 = mfma32(kB3, qf3, sa1);                 \
      __builtin_amdgcn_s_setprio(0);                                           \
    }                                                                           \
    const bool allones = fl[i_] != 0;                                           \
    float pv0[16], pv1[16];                                                     \
    if (allones) {                                                              \
      _Pragma("unroll")                                                         \
      for (int r = 0; r < 16; ++r) {                                            \
        pv0[r] = exp2f(sa0[r] * C2);                                            \
        pv1[r] = exp2f(sa1[r] * C2);                                            \
      }                                                                         \
    } else {                                                                    \
      int qq = q0 + qg * 32 + l31;                                              \
      int kt64 = (kh * 16 + i_) * 64;                                           \
      _Pragma("unroll")                                                         \
      for (int r = 0; r < 16; ++r) {                                            \
        int krow = (r & 3) + 8 * (r >> 2) + 4 * h;                              \
        float mv0 = mbase[(size_t)qq * SS + kt64 + krow];                       \
        float mv1 = mbase[(size_t)qq * SS + kt64 + 32 + krow];                  \
        float s0 = sa0[r] * 0.125f, s1 = sa1[r] * 0.125f;                       \
        pv0[r] = exp2f((s0 * mv0 - 10000.f * (1.f - mv0)) * LOG2E);             \
        pv1[r] = exp2f((s1 * mv1 - 10000.f * (1.f - mv1)) * LOG2E);             \
      }                                                                         \
    }                                                                           \
    {                                                                           \
      float t0 = 0.f, t1 = 0.f;                                                 \
      _Pragma("unroll")                                                         \
      for (int r = 0; r < 16; r += 4)                                           \
        t0 += (pv0[r] + pv0[r+1]) + (pv0[r+2] + pv0[r+3]);                      \
      _Pragma("unroll")                                                         \
      for (int r = 0; r < 16; r += 4)                                           \
        t1 += (pv1[r] + pv1[r+1]) + (pv1[r+2] + pv1[r+3]);                      \
      lsum += t0 + t1;                                                          \
    }                                                                           \
    /* pack P to bf16 + cross-half exchange (R4-verified layout) */             \
    unsigned int Lo[2][4], Hi[2][4];                                            \
    _Pragma("unroll")                                                           \
    for (int m = 0; m < 4; ++m) {                                               \
      Lo[0][m] = cvtpk(pv0[4*m+0], pv0[4*m+1]);                                 \
      Hi[0][m] = cvtpk(pv0[4*m+2], pv0[4*m+3]);                                 \
      Lo[1][m] = cvtpk(pv1[4*m+0], pv1[4*m+1]);                                 \
      Hi[1][m] = cvtpk(pv1[4*m+2], pv1[4*m+3]);                                 \
    }                                                                           \
    bf16x8 pa[4];                                                               \
    _Pragma("unroll")                                                           \
    for (int ks = 0; ks < 4; ++ks) {                                            \
      int kb = ks >> 1, s = ks & 1;                                             \
      unsigned int sendL = h ? Lo[kb][2*s] : Lo[kb][2*s+1];                     \
      unsigned int recvL = __shfl_xor(sendL, 32, 64);                           \
      unsigned int w0 = h ? recvL : Lo[kb][2*s];                                \
      unsigned int w2 = h ? Lo[kb][2*s+1] : recvL;                              \
      unsigned int sendH = h ? Hi[kb][2*s] : Hi[kb][2*s+1];                     \
      unsigned int recvH = __shfl_xor(sendH, 32, 64);                           \
      unsigned int w1 = h ? recvH : Hi[kb][2*s];                                \
      unsigned int w3 = h ? Hi[kb][2*s+1] : recvH;                              \
      union { bf16x8 v; unsigned int w[4]; } U;                                 \
      U.w[0] = w0; U.w[1] = w1; U.w[2] = w2; U.w[3] = w3;                       \
      pa[ks] = U.v;                                                             \
    }                                                                           \
    /* PV: O[32q][64d] += P . V */                                              \
    {                                                                           \
      bf16x8 bv00 = *reinterpret_cast<const bf16x8*>(Vr0 + (CUR_)*4096 + o0);   \
      bf16x8 bv10 = *reinterpret_cast<const bf16x8*>(Vr1 + (CUR_)*4096 + o0);   \
      bf16x8 bv01 = *reinterpret_cast<const bf16x8*>(Vr0 + (CUR_)*4096 + o1);   \
      bf16x8 bv11 = *reinterpret_cast<const bf16x8*>(Vr1 + (CUR_)*4096 + o1);   \
      bf16x8 bv02 = *reinterpret_cast<const bf16x8*>(Vr0 + (CUR_)*4096 + o2);   \
      bf16x8 bv12 = *reinterpret_cast<const bf16x8*>(Vr1 + (CUR_)*4096 + o2);   \
      bf16x8 bv03 = *reinterpret_cast<const bf16x8*>(Vr0 + (CUR_)*4096 + o3);   \
      bf16x8 bv13 = *reinterpret_cast<const bf16x8*>(Vr1 + (CUR_)*4096 + o3);   \
      __builtin_amdgcn_s_setprio(1);                                           \
      oacc0 = mfma32(pa[0], bv00, oacc0); oacc1 = mfma32(pa[0], bv10, oacc1);   \
      oacc0 = mfma32(pa[1], bv01, oacc0); oacc1 = mfma32(pa[1], bv11, oacc1);   \
      oacc0 = mfma32(pa[2], bv02, oacc0); oacc1 = mfma32(pa[2], bv12, oacc1);   \
      oacc0 = mfma32(pa[3], bv03, oacc0); oacc1 = mfma32(pa[3], bv13, oacc1);   \
      __builtin_amdgcn_s_setprio(0);                                           \
    }                                                                           \
    __syncthreads();                                                            \
  }

  for (int it = 0; it < 16; it += 2) {
    TILE(0, it, true)                    // it <= 14 -> it+1 <= 15 always staged
    TILE(1, it + 1, (it + 2 < 16))
  }
#undef TILE

  // ---- split-K merge (max-free: pure add) ----
  // Ms[qg][i][lane] overlays Ks (32KB); Ls[qg][lane] overlays Vs.
  float* Ms = reinterpret_cast<float*>(&Ks[0][0][0]);
  float* Ls = reinterpret_cast<float*>(&Vs[0][0][0]);
  if (kh == 1) {
#pragma unroll
    for (int i = 0; i < 16; ++i) {
      Ms[(qg * 32 + i) * 64 + lane] = oacc0[i];
      Ms[(qg * 32 + 16 + i) * 64 + lane] = oacc1[i];
    }
    Ls[qg * 64 + lane] = lsum;
  }
  __syncthreads();
  if (kh == 0) {
#pragma unroll
    for (int i = 0; i < 16; ++i) {
      oacc0[i] += Ms[(qg * 32 + i) * 64 + lane];
      oacc1[i] += Ms[(qg * 32 + 16 + i) * 64 + lane];
    }
    lsum += Ls[qg * 64 + lane];
    lsum += __shfl_xor(lsum, 32, 64);
    float invl = 1.f / lsum;             // valid at lanes l31 / l31+32 for q = l31
#pragma unroll
    for (int r = 0; r < 16; ++r) {
      int qr = (r & 3) + 8 * (r >> 2) + 4 * h;
      float inv = __shfl(invl, qr, 64);
      int qq = q0 + qg * 32 + qr;
      unsigned short* cp = ctx + (size_t)(b * SS + qq) * HH + hh * HDD;
      cp[l31] = f2bfu(oacc0[r] * inv);
      cp[32 + l31] = f2bfu(oacc1[r] * inv);
    }
  }
}

extern "C" void kernel_launch(void* const* d_in, const int* in_sizes, int n_in,
                              void* d_out, int out_size, void* d_ws, size_t ws_size,
                              hipStream_t stream) {
  const float* hs      = (const float*)d_in[0];
  const float* mask    = (const float*)d_in[1];
  const float* qkv_w   = (const float*)d_in[2];
  const float* qkv_b   = (const float*)d_in[3];
  const float* dense_w = (const float*)d_in[4];
  const float* dense_b = (const float*)d_in[5];
  float* out = (float*)d_out;

  char* ws = (char*)d_ws;
  unsigned short* hs_b     = (unsigned short*)(ws);                 // 4096x1024 (8MB)
  unsigned short* qkvw_b   = (unsigned short*)(ws + 8388608);       // 3072x1024 (6MB)
  unsigned short* densew_b = (unsigned short*)(ws + 14680064);      // 1024x1024 (2MB)
  unsigned short* mixed_b  = (unsigned short*)(ws + 16777216);      // 4096x3072 (24MB)
  unsigned short* ctx_b    = (unsigned short*)(ws + 41943040);      // 4096x1024 (8MB)
  unsigned char*  flags    = (unsigned char*)(ws + 50331648);       // 2048 B
  unsigned short* vT_b     = (unsigned short*)(ws + 50335744);      // 8MB

  cvt3_f32_bf16<<<2048, 256, 0, stream>>>(hs, hs_b, (MM * HH) / 4,
                                          qkv_w, qkvw_b, (N1 * HH) / 4,
                                          dense_w, densew_b, (HH * HH) / 4);
  mask_flags_kernel<<<BB * 32 * 32, 256, 0, stream>>>(mask, flags);

  gemm_bt<true><<<dim3(MM / 128, N1 / 128), 256, 0, stream>>>(
      hs_b, qkvw_b, qkv_b, mixed_b, N1, HH);

  vtrans_kernel<<<dim3(SS / 64, BB * NHH), 256, 0, stream>>>(mixed_b, vT_b);

  attn_kernel<<<dim3(SS / 128, BB * NHH), 512, 0, stream>>>(
      mixed_b, vT_b, mask, flags, ctx_b);

  gemm_bt<false><<<dim3(MM / 128, HH / 128), 256, 0, stream>>>(
      ctx_b, densew_b, dense_b, out, HH, HH);
}

// Round 17
// 146.779 us; speedup vs baseline: 1.7975x; 1.7975x over previous
//
#include <hip/hip_runtime.h>
#include <hip/hip_bf16.h>
#include <stdint.h>

#define BB 2
#define SS 2048
#define HH 1024
#define NHH 16
#define HDD 64
#define MM (BB*SS)      // 4096
#define N1 (3*HH)       // 3072
#define NT (SS/64)      // 32 kv tiles
#define LOG2E 1.44269504f

using bf16 = __hip_bfloat16;
typedef __attribute__((ext_vector_type(8))) short bf16x8;
typedef __attribute__((ext_vector_type(4))) float f32x4;

__device__ inline unsigned short f2bfu(float f) {
  union { bf16 h; unsigned short u; } c;
  c.h = __float2bfloat16(f);
  return c.u;
}

// hardware packed f32->bf16 (RNE), src0 -> low16, src1 -> high16 (T12 recipe)
__device__ inline unsigned int cvtpk(float lo, float hi) {
  unsigned int r;
  asm("v_cvt_pk_bf16_f32 %0, %1, %2" : "=v"(r) : "v"(lo), "v"(hi));
  return r;
}

__device__ inline void load_lds16(const void* g, void* l) {
  __builtin_amdgcn_global_load_lds(
      (const __attribute__((address_space(1))) void*)g,
      (__attribute__((address_space(3))) void*)l, 16, 0, 0);
}

__device__ inline f32x4 mfma16(bf16x8 a, bf16x8 b, f32x4 c) {
  return __builtin_amdgcn_mfma_f32_16x16x32_bf16(a, b, c, 0, 0, 0);
}

// ---------------- prep: mask tile flags (blocks 0..2047) + fp32->bf16 cvt ----------
__global__ __launch_bounds__(256) void prep_kernel(const float* __restrict__ mask,
                                                   unsigned char* __restrict__ flags,
                                                   const float* __restrict__ a,
                                                   unsigned short* __restrict__ ao, int na4,
                                                   const float* __restrict__ bsrc,
                                                   unsigned short* __restrict__ bo, int nb4,
                                                   const float* __restrict__ c,
                                                   unsigned short* __restrict__ co, int nc4) {
  if (blockIdx.x < 2048) {
    // mask tile flags: 1 if 64x64 tile is all ones
    int t = blockIdx.x;
    int b = t >> 10, qt = (t >> 5) & 31, kt = t & 31;
    const float* mb = mask + ((size_t)b * SS + qt * 64) * SS + kt * 64;
    int row = threadIdx.x >> 2, c0 = (threadIdx.x & 3) * 16;
    int ok = 1;
#pragma unroll
    for (int j = 0; j < 4; ++j) {
      float4 v = *reinterpret_cast<const float4*>(mb + (size_t)row * SS + c0 + j * 4);
      ok &= (v.x == 1.f) & (v.y == 1.f) & (v.z == 1.f) & (v.w == 1.f);
    }
    ok = __all(ok);
    __shared__ int s[4];
    if ((threadIdx.x & 63) == 0) s[threadIdx.x >> 6] = ok;
    __syncthreads();
    if (threadIdx.x == 0) flags[t] = (unsigned char)(s[0] & s[1] & s[2] & s[3]);
    return;
  }
  // fused convert over 3 buffers
  int total = na4 + nb4 + nc4;
  int nblk = gridDim.x - 2048;
  int st = nblk * blockDim.x;
  for (int i = (blockIdx.x - 2048) * blockDim.x + threadIdx.x; i < total; i += st) {
    const float* in; unsigned short* out; int j = i;
    if (j < na4) { in = a; out = ao; }
    else if (j < na4 + nb4) { j -= na4; in = bsrc; out = bo; }
    else { j -= na4 + nb4; in = c; out = co; }
    float4 v = reinterpret_cast<const float4*>(in)[j];
    ushort4 o;
    o.x = f2bfu(v.x); o.y = f2bfu(v.y); o.z = f2bfu(v.z); o.w = f2bfu(v.w);
    reinterpret_cast<ushort4*>(out)[j] = o;
  }
}

// ---------------- V transpose: mixed V-cols -> vT[b][h][d][s] ----------------
__global__ __launch_bounds__(256) void vtrans_kernel(const unsigned short* __restrict__ mixed,
                                                     unsigned short* __restrict__ vT) {
  __shared__ unsigned short t[64 * 72];
  const int st = blockIdx.x, bh = blockIdx.y;
  const int b = bh >> 4, h = bh & 15;
  const int r = threadIdx.x >> 2, c0 = (threadIdx.x & 3) * 16;

  const unsigned short* src = mixed + ((size_t)(b * SS) + st * 64) * N1 + h * 192 + 128;
  union { bf16x8 v; unsigned short u[8]; } A, B;
  A.v = *reinterpret_cast<const bf16x8*>(src + (size_t)r * N1 + c0);
  B.v = *reinterpret_cast<const bf16x8*>(src + (size_t)r * N1 + c0 + 8);
#pragma unroll
  for (int j = 0; j < 8; ++j) t[(c0 + j) * 72 + r] = A.u[j];
#pragma unroll
  for (int j = 0; j < 8; ++j) t[(c0 + 8 + j) * 72 + r] = B.u[j];
  __syncthreads();

  unsigned short* dst = vT + ((size_t)bh * HDD + r) * SS + st * 64 + c0;
  bf16x8 o0 = *reinterpret_cast<const bf16x8*>(&t[r * 72 + c0]);
  bf16x8 o1 = *reinterpret_cast<const bf16x8*>(&t[r * 72 + c0 + 8]);
  *reinterpret_cast<bf16x8*>(dst) = o0;
  *reinterpret_cast<bf16x8*>(dst + 8) = o1;
}

// ---------------- GEMM (R13, verified): 128x128, BK=64, XOR-swizzled LDS ------------
template <bool OUT_BF16>
__global__ __launch_bounds__(256) void gemm_bt(const unsigned short* __restrict__ A,
                                               const unsigned short* __restrict__ Bt,
                                               const float* __restrict__ bias,
                                               void* __restrict__ Cv,
                                               int Ndim, int Kdim) {
  __shared__ __align__(16) unsigned short As[128 * 64];
  __shared__ __align__(16) unsigned short Bs[128 * 64];

  const int tid = threadIdx.x;
  const int wave = tid >> 6, lane = tid & 63;
  const int m0 = blockIdx.x * 128;
  const int n0 = blockIdx.y * 128;
  const int wm = (wave >> 1) * 64, wn = (wave & 1) * 64;
  const int lrow = lane & 15;
  const int g = lane >> 4;
  const int r4 = (lane >> 4) * 4;
  const int x0 = (g ^ (lrow & 7)) << 3;
  const int x1 = ((g + 4) ^ (lrow & 7)) << 3;

  f32x4 acc[4][4];
  const f32x4 z = {0.f, 0.f, 0.f, 0.f};
  for (int i = 0; i < 4; ++i)
    for (int j = 0; j < 4; ++j) acc[i][j] = z;

  for (int k0 = 0; k0 < Kdim; k0 += 64) {
#pragma unroll
    for (int it = 0; it < 4; ++it) {
      int idx = it * 256 + tid;
      int row = idx >> 3, seg = idx & 7;
      int sw = (seg ^ (row & 7)) << 3;
      load_lds16(A + (size_t)(m0 + row) * Kdim + k0 + sw, &As[row * 64 + seg * 8]);
      load_lds16(Bt + (size_t)(n0 + row) * Kdim + k0 + sw, &Bs[row * 64 + seg * 8]);
    }
    __syncthreads();

    bf16x8 af[4], bfr[4];
#pragma unroll
    for (int i = 0; i < 4; ++i)
      af[i] = *reinterpret_cast<const bf16x8*>(&As[(wm + i * 16 + lrow) * 64 + x0]);
#pragma unroll
    for (int j = 0; j < 4; ++j)
      bfr[j] = *reinterpret_cast<const bf16x8*>(&Bs[(wn + j * 16 + lrow) * 64 + x0]);
#pragma unroll
    for (int i = 0; i < 4; ++i)
#pragma unroll
      for (int j = 0; j < 4; ++j)
        acc[i][j] = mfma16(af[i], bfr[j], acc[i][j]);
#pragma unroll
    for (int i = 0; i < 4; ++i)
      af[i] = *reinterpret_cast<const bf16x8*>(&As[(wm + i * 16 + lrow) * 64 + x1]);
#pragma unroll
    for (int j = 0; j < 4; ++j)
      bfr[j] = *reinterpret_cast<const bf16x8*>(&Bs[(wn + j * 16 + lrow) * 64 + x1]);
#pragma unroll
    for (int i = 0; i < 4; ++i)
#pragma unroll
      for (int j = 0; j < 4; ++j)
        acc[i][j] = mfma16(af[i], bfr[j], acc[i][j]);
    __syncthreads();
  }

#pragma unroll
  for (int i = 0; i < 4; ++i) {
#pragma unroll
    for (int j = 0; j < 4; ++j) {
      int col = n0 + wn + j * 16 + lrow;
      float bv = bias[col];
#pragma unroll
      for (int r = 0; r < 4; ++r) {
        int row = m0 + wm + i * 16 + r4 + r;
        float v = acc[i][j][r] + bv;
        if (OUT_BF16) {
          ((unsigned short*)Cv)[(size_t)row * Ndim + col] = f2bfu(v);
        } else {
          ((float*)Cv)[(size_t)row * Ndim + col] = v;
        }
      }
    }
  }
}

// ---------------- Flash attention (R9 structure + early V-fragment loads) -----------
// Block 256 = 4 waves; Q-tile 64 (wave owns 16 q-rows); KVBLK 64; grid (32, B*NH).
// Swapped QK^T (mfma16(K,Q) -> D[krow][q], q=lane&15), max-free softmax,
// 2x-unrolled kt loop, precomputed LDS pointers, cvt_pk P-pack, deferred l-sum.
// NEW: PV's 8 V-fragment LDS reads issued right after QK^T (latency hidden under
// softmax VALU); lsum tree moved after P-writes to cover the P ds_write->ds_read gap.
__global__ __launch_bounds__(256, 4) void attn_kernel(const unsigned short* __restrict__ mixed,
                                                      const unsigned short* __restrict__ vT,
                                                      const float* __restrict__ mask,
                                                      const unsigned char* __restrict__ flags,
                                                      unsigned short* __restrict__ ctx) {
  __shared__ __align__(16) unsigned short Ks[2][64 * 64];
  __shared__ __align__(16) unsigned short Vt[2][64 * 64];   // [d][s]
  __shared__ __align__(16) unsigned short QP[64 * 64];      // Q tile, then P (per-wave)

  const int tid = threadIdx.x, wave = tid >> 6, lane = tid & 63;
  const int ql = lane & 15;
  const int g = lane >> 4;
  const int q0 = blockIdx.x * 64;
  const int bh = blockIdx.y;
  const int b = bh / NHH, hh = bh % NHH;

  const unsigned short* qbase = mixed + (size_t)(b * SS) * N1 + hh * 192;
  const unsigned short* kbase = qbase + 64;
  const unsigned short* vtbase = vT + ((size_t)(b * NHH + hh) * HDD) * SS;  // [d][s]
  const float* mbase = mask + (size_t)b * SS * SS;
  const unsigned char* fl = flags + ((size_t)b * 32 + blockIdx.x) * 32;

  const int srow = tid >> 3, sseg = tid & 7;
  const int swst = (sseg ^ (srow & 7)) << 3;

  // ---- prologue: stage Q, K0, V0 ----
  load_lds16(qbase + (size_t)(q0 + srow) * N1 + swst, &QP[srow * 64 + sseg * 8]);
  load_lds16(qbase + (size_t)(q0 + 32 + srow) * N1 + swst, &QP[(32 + srow) * 64 + sseg * 8]);
  load_lds16(kbase + (size_t)srow * N1 + swst, &Ks[0][srow * 64 + sseg * 8]);
  load_lds16(kbase + (size_t)(32 + srow) * N1 + swst, &Ks[0][(32 + srow) * 64 + sseg * 8]);
  load_lds16(vtbase + (size_t)srow * SS + swst, &Vt[0][srow * 64 + sseg * 8]);
  load_lds16(vtbase + (size_t)(32 + srow) * SS + swst, &Vt[0][(32 + srow) * 64 + sseg * 8]);
  __syncthreads();

  // ---- hoist Q fragments ----
  const int qrow = wave * 16 + ql;
  const bf16x8 qf0 = *reinterpret_cast<const bf16x8*>(
      &QP[qrow * 64 + ((g ^ (qrow & 7)) << 3)]);
  const bf16x8 qf1 = *reinterpret_cast<const bf16x8*>(
      &QP[qrow * 64 + (((g + 4) ^ (qrow & 7)) << 3)]);
  __syncthreads();   // everyone done reading Q before P overwrites it

  // ---- precomputed loop-invariant LDS pointers ----
  const int s0 = (g ^ (ql & 7)) << 3;
  const int s1 = ((g + 4) ^ (ql & 7)) << 3;
  const unsigned short* KrA = &Ks[0][ql * 64 + s0];   // + CUR*4096 + n*1024
  const unsigned short* KrB = &Ks[0][ql * 64 + s1];
  const unsigned short* VrA = &Vt[0][ql * 64 + s0];   // + CUR*4096 + fd*1024
  const unsigned short* VrB = &Vt[0][ql * 64 + s1];
  unsigned short* Ps = &QP[wave * 1024];
  const int X = (ql & 7) << 3;
  unsigned short* Pw0 = &Ps[ql * 64 + ((4 * g) ^ X)];
  unsigned short* Pw1 = &Ps[ql * 64 + ((16 + 4 * g) ^ X)];
  unsigned short* Pw2 = &Ps[ql * 64 + ((32 + 4 * g) ^ X)];
  unsigned short* Pw3 = &Ps[ql * 64 + ((48 + 4 * g) ^ X)];
  const unsigned short* Pr0 = &Ps[ql * 64 + ((8 * g) ^ X)];
  const unsigned short* Pr1 = &Ps[ql * 64 + ((32 + 8 * g) ^ X)];

  // ---- loop-carried global prefetch pointers ----
  const unsigned short* kpre = kbase + (size_t)(64 + srow) * N1 + swst;
  const unsigned short* vpre = vtbase + (size_t)srow * SS + 64 + swst;

  f32x4 oacc[4];
  const f32x4 z = {0.f, 0.f, 0.f, 0.f};
  for (int fd = 0; fd < 4; ++fd) oacc[fd] = z;
  float lsum = 0.f;
  const float C2 = 0.125f * LOG2E;

#define TILE_BODY(CUR_, KT_, HAVENEXT_)                                         \
  {                                                                             \
    const int kt_ = (KT_);                                                      \
    if (HAVENEXT_) {                                                            \
      load_lds16(kpre, &Ks[(CUR_)^1][srow * 64 + sseg * 8]);                    \
      load_lds16(kpre + 32 * N1, &Ks[(CUR_)^1][(32 + srow) * 64 + sseg * 8]);   \
      load_lds16(vpre, &Vt[(CUR_)^1][srow * 64 + sseg * 8]);                    \
      load_lds16(vpre + 32 * SS, &Vt[(CUR_)^1][(32 + srow) * 64 + sseg * 8]);   \
    }                                                                           \
    kpre += 64 * N1; vpre += 64;                                                \
    f32x4 sacc[4];                                                              \
    __builtin_amdgcn_s_setprio(1);                                              \
    _Pragma("unroll")                                                           \
    for (int n = 0; n < 4; ++n) {                                               \
      bf16x8 k0 = *reinterpret_cast<const bf16x8*>(KrA + (CUR_)*4096 + n*1024); \
      bf16x8 k1 = *reinterpret_cast<const bf16x8*>(KrB + (CUR_)*4096 + n*1024); \
      sacc[n] = mfma16(k0, qf0, z);                                             \
      sacc[n] = mfma16(k1, qf1, sacc[n]);                                       \
    }                                                                           \
    __builtin_amdgcn_s_setprio(0);                                              \
    /* early V-fragment loads: LDS latency hides under softmax VALU */          \
    bf16x8 bv00 = *reinterpret_cast<const bf16x8*>(VrA + (CUR_)*4096 + 0*1024); \
    bf16x8 bv10 = *reinterpret_cast<const bf16x8*>(VrB + (CUR_)*4096 + 0*1024); \
    bf16x8 bv01 = *reinterpret_cast<const bf16x8*>(VrA + (CUR_)*4096 + 1*1024); \
    bf16x8 bv11 = *reinterpret_cast<const bf16x8*>(VrB + (CUR_)*4096 + 1*1024); \
    bf16x8 bv02 = *reinterpret_cast<const bf16x8*>(VrA + (CUR_)*4096 + 2*1024); \
    bf16x8 bv12 = *reinterpret_cast<const bf16x8*>(VrB + (CUR_)*4096 + 2*1024); \
    bf16x8 bv03 = *reinterpret_cast<const bf16x8*>(VrA + (CUR_)*4096 + 3*1024); \
    bf16x8 bv13 = *reinterpret_cast<const bf16x8*>(VrB + (CUR_)*4096 + 3*1024); \
    const bool allones = fl[kt_] != 0;                                          \
    float pv[4][4];                                                             \
    if (allones) {                                                              \
      _Pragma("unroll")                                                         \
      for (int n = 0; n < 4; ++n)                                               \
        _Pragma("unroll")                                                       \
        for (int r = 0; r < 4; ++r)                                             \
          pv[n][r] = exp2f(sacc[n][r] * C2);                                    \
    } else {                                                                    \
      int qq = q0 + wave * 16 + ql;                                             \
      _Pragma("unroll")                                                         \
      for (int n = 0; n < 4; ++n)                                               \
        _Pragma("unroll")                                                       \
        for (int r = 0; r < 4; ++r) {                                           \
          int kk = kt_ * 64 + 16 * n + 4 * g + r;                               \
          float mv = mbase[(size_t)qq * SS + kk];                               \
          float s = sacc[n][r] * 0.125f;                                        \
          pv[n][r] = exp2f((s * mv - 10000.f * (1.f - mv)) * LOG2E);            \
        }                                                                       \
    }                                                                           \
    { uint2 w; w.x = cvtpk(pv[0][0], pv[0][1]); w.y = cvtpk(pv[0][2], pv[0][3]);\
      *reinterpret_cast<uint2*>(Pw0) = w; }                                     \
    { uint2 w; w.x = cvtpk(pv[1][0], pv[1][1]); w.y = cvtpk(pv[1][2], pv[1][3]);\
      *reinterpret_cast<uint2*>(Pw1) = w; }                                     \
    { uint2 w; w.x = cvtpk(pv[2][0], pv[2][1]); w.y = cvtpk(pv[2][2], pv[2][3]);\
      *reinterpret_cast<uint2*>(Pw2) = w; }                                     \
    { uint2 w; w.x = cvtpk(pv[3][0], pv[3][1]); w.y = cvtpk(pv[3][2], pv[3][3]);\
      *reinterpret_cast<uint2*>(Pw3) = w; }                                     \
    /* lsum tree after P-writes: covers ds_write->ds_read gap */                \
    {                                                                           \
      float t00 = (pv[0][0] + pv[0][1]) + (pv[0][2] + pv[0][3]);                \
      float t01 = (pv[1][0] + pv[1][1]) + (pv[1][2] + pv[1][3]);                \
      float t10 = (pv[2][0] + pv[2][1]) + (pv[2][2] + pv[2][3]);                \
      float t11 = (pv[3][0] + pv[3][1]) + (pv[3][2] + pv[3][3]);                \
      lsum += (t00 + t01) + (t10 + t11);                                        \
    }                                                                           \
    bf16x8 pa0 = *reinterpret_cast<const bf16x8*>(Pr0);                         \
    bf16x8 pa1 = *reinterpret_cast<const bf16x8*>(Pr1);                         \
    __builtin_amdgcn_s_setprio(1);                                              \
    oacc[0] = mfma16(pa0, bv00, oacc[0]);                                       \
    oacc[1] = mfma16(pa0, bv01, oacc[1]);                                       \
    oacc[2] = mfma16(pa0, bv02, oacc[2]);                                       \
    oacc[3] = mfma16(pa0, bv03, oacc[3]);                                       \
    oacc[0] = mfma16(pa1, bv10, oacc[0]);                                       \
    oacc[1] = mfma16(pa1, bv11, oacc[1]);                                       \
    oacc[2] = mfma16(pa1, bv12, oacc[2]);                                       \
    oacc[3] = mfma16(pa1, bv13, oacc[3]);                                       \
    __builtin_amdgcn_s_setprio(0);                                              \
    __syncthreads();                                                            \
  }

  for (int kt = 0; kt < NT; kt += 2) {
    TILE_BODY(0, kt, true)                 // kt <= 30 -> kt+1 < 32 always
    TILE_BODY(1, kt + 1, (kt + 2 < NT))
  }
#undef TILE_BODY

  // ---- epilogue: reduce l across groups, gather per-row, store ----
  float lrun = lsum;
  lrun += __shfl_xor(lrun, 16, 64);
  lrun += __shfl_xor(lrun, 32, 64);
  float invl = 1.f / lrun;   // valid for q = ql at this lane
#pragma unroll
  for (int r = 0; r < 4; ++r) {
    float inv = __shfl(invl, g * 4 + r, 64);
    int qq = q0 + wave * 16 + g * 4 + r;
    unsigned short* cp = ctx + (size_t)(b * SS + qq) * HH + hh * HDD;
#pragma unroll
    for (int fd = 0; fd < 4; ++fd)
      cp[fd * 16 + ql] = f2bfu(oacc[fd][r] * inv);
  }
}

extern "C" void kernel_launch(void* const* d_in, const int* in_sizes, int n_in,
                              void* d_out, int out_size, void* d_ws, size_t ws_size,
                              hipStream_t stream) {
  const float* hs      = (const float*)d_in[0];
  const float* mask    = (const float*)d_in[1];
  const float* qkv_w   = (const float*)d_in[2];
  const float* qkv_b   = (const float*)d_in[3];
  const float* dense_w = (const float*)d_in[4];
  const float* dense_b = (const float*)d_in[5];
  float* out = (float*)d_out;

  char* ws = (char*)d_ws;
  unsigned short* hs_b     = (unsigned short*)(ws);                 // 4096x1024 (8MB)
  unsigned short* qkvw_b   = (unsigned short*)(ws + 8388608);       // 3072x1024 (6MB)
  unsigned short* densew_b = (unsigned short*)(ws + 14680064);      // 1024x1024 (2MB)
  unsigned short* mixed_b  = (unsigned short*)(ws + 16777216);      // 4096x3072 (24MB)
  unsigned short* ctx_b    = (unsigned short*)(ws + 41943040);      // 4096x1024 (8MB)
  unsigned char*  flags    = (unsigned char*)(ws + 50331648);       // 2048 B
  unsigned short* vT_b     = (unsigned short*)(ws + 50335744);      // 8MB

  // prep: mask flags (blocks 0..2047) + fused cvt (blocks 2048..4095)
  prep_kernel<<<4096, 256, 0, stream>>>(mask, flags,
                                        hs, hs_b, (MM * HH) / 4,
                                        qkv_w, qkvw_b, (N1 * HH) / 4,
                                        dense_w, densew_b, (HH * HH) / 4);

  gemm_bt<true><<<dim3(MM / 128, N1 / 128), 256, 0, stream>>>(
      hs_b, qkvw_b, qkv_b, mixed_b, N1, HH);

  vtrans_kernel<<<dim3(SS / 64, BB * NHH), 256, 0, stream>>>(mixed_b, vT_b);

  attn_kernel<<<dim3(SS / 64, BB * NHH), 256, 0, stream>>>(
      mixed_b, vT_b, mask, flags, ctx_b);

  gemm_bt<false><<<dim3(MM / 128, HH / 128), 256, 0, stream>>>(
      ctx_b, densew_b, dense_b, out, HH, HH);
}